// Round 1
// baseline (310.350 us; speedup 1.0000x reference)
//
#include <hip/hip_runtime.h>

// Grouped 1x7 conv, NCHW, N=128 C=24 H=W=112, groups=2 (12 ic/oc per group),
// pad (3,3) on W, then roll(+1) on H folded into the output row index.
// y[n,o,h,w] = sum_{i,t} x[n, g*12+i, h, w+t-3] * wgt[i, o%12, t],  g=o/12
// out[n,o,(h+1)%112,w] = y[n,o,h,w]
//
// One thread = one W-quad (4 outputs) x all 12 oc of its group -> 48 accs.
// x is read once from HBM; weights go through scalar loads (wave-uniform).

#define HW 112
#define CHSTRIDE (112 * 112)   // 12544 floats per (n,c) plane
#define QPR 28                 // quads per row (112/4)

__global__ __launch_bounds__(256) void conv1x7_grouped_roll(
    const float* __restrict__ x,
    const float* __restrict__ wgt,   // [12][12][7] : [ic][oc][tap]
    float* __restrict__ out)
{
    int qid = blockIdx.x * 256 + threadIdx.x;   // 802816 quads total, exact grid
    int w0q = qid % QPR;
    int tmp = qid / QPR;
    int h   = tmp % HW;
    tmp    /= HW;
    int g   = tmp & 1;        // group 0/1
    int n   = tmp >> 1;       // batch
    int w0  = w0q * 4;

    const float* xbase = x + ((size_t)(n * 24 + g * 12) * HW + h) * HW;

    float acc[12][4];
    #pragma unroll
    for (int o = 0; o < 12; ++o)
        #pragma unroll
        for (int p = 0; p < 4; ++p) acc[o][p] = 0.f;

    // masks for the 10-float window [w0-3, w0+6]; hoisted out of the ic loop
    bool ok[10];
    int  idx[10];
    #pragma unroll
    for (int t = 0; t < 10; ++t) {
        int wi = w0 - 3 + t;
        ok[t]  = (unsigned)wi < (unsigned)HW;
        idx[t] = ok[t] ? wi : 0;   // clamped, always-safe address
    }

    for (int ic = 0; ic < 12; ++ic) {
        const float* xr = xbase + (size_t)ic * CHSTRIDE;
        float xv[10];
        #pragma unroll
        for (int t = 0; t < 10; ++t) {
            float v = xr[idx[t]];
            xv[t] = ok[t] ? v : 0.f;
        }
        const float* wr = wgt + ic * 84;   // 84 wave-uniform floats -> s_load
        #pragma unroll
        for (int o = 0; o < 12; ++o) {
            #pragma unroll
            for (int t = 0; t < 7; ++t) {
                float wv = wr[o * 7 + t];
                #pragma unroll
                for (int p = 0; p < 4; ++p)
                    acc[o][p] = fmaf(xv[t + p], wv, acc[o][p]);
            }
        }
    }

    int ho = h + 1; if (ho >= HW) ho = 0;            // roll(+1) on H
    float* ob = out + ((size_t)(n * 24 + g * 12) * HW + ho) * HW + w0;
    #pragma unroll
    for (int o = 0; o < 12; ++o) {
        float4 v = make_float4(acc[o][0], acc[o][1], acc[o][2], acc[o][3]);
        *reinterpret_cast<float4*>(ob + (size_t)o * CHSTRIDE) = v;
    }
}

extern "C" void kernel_launch(void* const* d_in, const int* in_sizes, int n_in,
                              void* d_out, int out_size, void* d_ws, size_t ws_size,
                              hipStream_t stream)
{
    const float* x = (const float*)d_in[0];   // 128*24*112*112
    const float* w = (const float*)d_in[1];   // 12*12*7
    float* out = (float*)d_out;               // 128*24*112*112

    // total quads = 128 * 2 * 112 * 28 = 802816 = 3136 blocks * 256 threads
    dim3 grid(3136), block(256);
    hipLaunchKernelGGL(conv1x7_grouped_roll, grid, block, 0, stream, x, w, out);
}